// Round 5
// baseline (28078.799 us; speedup 1.0000x reference)
//
#include <hip/hip_runtime.h>
#include <math.h>

#define D_IN   512
#define HID    1024
#define SEQ    512
#define NBATCH 64
#define K3     3072
#define KTOT   1536
#define WB_ELEMS (K3 * KTOT)
#define NBLK   256
#define BLOCK_T 704   // 11 waves: 0-7 h-GEMM (K=128 each), 8-10 x-producer (1 gate each)

typedef __attribute__((ext_vector_type(8))) short short8;
typedef __attribute__((ext_vector_type(4))) float f32x4;

#define MFMA(a, b, c) __builtin_amdgcn_mfma_f32_16x16x32_bf16((a), (b), (c), 0, 0, 0)

// ---------------- build fused transposed weight planes (hi/lo bf16) ----------------
__global__ __launch_bounds__(256) void build_wt(const float* __restrict__ Win,
                                                const float* __restrict__ Wh,
                                                __bf16* __restrict__ WBh,
                                                __bf16* __restrict__ WBl) {
    int idx = blockIdx.x * 256 + threadIdx.x;
    if (idx >= WB_ELEMS) return;
    int k   = idx % KTOT;
    int col = idx / KTOT;
    float v = (k < D_IN) ? Win[(size_t)k * K3 + col]
                         : Wh[(size_t)(k - D_IN) * K3 + col];
    __bf16 hi = (__bf16)v;
    WBh[idx] = hi;
    WBl[idx] = (__bf16)(v - (float)hi);
}

__device__ __forceinline__ void cvt8(const f32x4& v0, const f32x4& v1,
                                     short8& ahi, short8& alo) {
    float af[8] = {v0[0], v0[1], v0[2], v0[3], v1[0], v1[1], v1[2], v1[3]};
    #pragma unroll
    for (int j = 0; j < 8; ++j) {
        __bf16 hb = (__bf16)af[j];
        __bf16 lb = (__bf16)(af[j] - (float)hb);
        ahi[j] = __builtin_bit_cast(short, hb);
        alo[j] = __builtin_bit_cast(short, lb);
    }
}

// x-producer: one gate, full K=512, result -> ring slot (16x16 tile, 4 regs/lane)
__device__ __forceinline__ void xproj_gate(const float* __restrict__ x,
                                           const __bf16* __restrict__ WBh,
                                           const __bf16* __restrict__ WBl,
                                           int m, int tp, int koff, int colz_g,
                                           float* __restrict__ ringslot, int l) {
    f32x4 acc = {0.f, 0.f, 0.f, 0.f};
    #pragma unroll
    for (int s = 0; s < 16; ++s) {
        const int ks = s * 32;
        const float* ap = x + ((size_t)m * SEQ + tp) * D_IN + ks + koff;
        f32x4 v0 = *(const f32x4*)ap;
        f32x4 v1 = *(const f32x4*)(ap + 4);
        short8 ahi, alo;
        cvt8(v0, v1, ahi, alo);
        const size_t o = (size_t)colz_g * KTOT + ks + koff;
        short8 bh = *(const short8*)(WBh + o);
        short8 bl = *(const short8*)(WBl + o);
        acc = MFMA(ahi, bh, acc);
        acc = MFMA(ahi, bl, acc);
        acc = MFMA(alo, bh, acc);
    }
    #pragma unroll
    for (int r = 0; r < 4; ++r) ringslot[r * 64 + l] = acc[r];
}

// ---------------- persistent GRU ----------------
// Grid 256 x 704. Block (mq=j&3, nb=xcd+8*(j>>2)), xcd=bid&7.
// h-waves 0-7: K-slice [512+128w, +128); x-waves 8-10: gate w-8, K=512, 2 steps ahead.
// Epilogue: tid<256 (h-waves 0-3). Barrier: 4 mq-domains, 4 arrivals/block/step,
// target (t+1)*256; per-wave polling, ONE __syncthreads per step.
__global__ __launch_bounds__(BLOCK_T, 3) void gru_persist(
        const float* __restrict__ x, const float* __restrict__ bin,
        const __bf16* __restrict__ WBh, const __bf16* __restrict__ WBl,
        float* __restrict__ out, unsigned* __restrict__ bar) {
    __shared__ float red[8][3][4][64];    // h-wave partials: 24KB
    __shared__ float ring[4][3][4][64];   // x_proj ring (4 slots x 3 gates): 12KB
    float* hall = out + NBATCH * HID;

    const int tid = threadIdx.x;
    const int l   = tid & 63;
    const int w   = tid >> 6;              // 0..10
    const int xcd = blockIdx.x & 7;
    const int j   = blockIdx.x >> 3;
    const int nb  = xcd + 8 * (j >> 2);
    const int mq  = j & 3;
    const int cb  = nb * 16;

    const int m    = mq * 16 + (l & 15);
    const int koff = (l >> 4) * 8;
    const int colz = cb + (l & 15);
    const bool isH = (w < 8);
    const int kw0  = D_IN + w * 128;       // h-wave K start (global k)

    unsigned* dbar = bar + mq * 32;        // domain counter (line-separated)

    // epilogue constants
    const int r2 = tid >> 6;
    const int l2 = tid & 63;
    const int be = mq * 16 + (l2 >> 4) * 4 + r2;   // C layout (m89)
    const int ce = cb + (l2 & 15);
    float bz = 0.f, br = 0.f, bnb = 0.f, hreg = 0.f;
    if (tid < 256) {
        bz  = bin[ce];
        br  = bin[HID + ce];
        bnb = bin[2 * HID + ce];
    }

    // ---- pre-loop: x-waves fill ring slots 0,1
    if (!isH) {
        const int colz_g = colz + (w - 8) * HID;
        xproj_gate(x, WBh, WBl, m, 0, koff, colz_g, &ring[0][w - 8][0][0], l);
        xproj_gate(x, WBh, WBl, m, 1, koff, colz_g, &ring[1][w - 8][0][0], l);
    }
    __syncthreads();

    for (int t = 0; t < SEQ; ++t) {
        if (isH) {
            f32x4 aZ = {0.f,0.f,0.f,0.f}, aR = {0.f,0.f,0.f,0.f}, aN = {0.f,0.f,0.f,0.f};
            if (t > 0) {
                const float* hp = hall + ((size_t)m * SEQ + (t - 1)) * HID + (kw0 - D_IN) + koff;
                f32x4 h0, h1, h2, h3, h4, h5, h6, h7;
                // issue all 8, wait once (waitcnt inside same asm -> ordered w.r.t. uses)
                asm volatile(
                    "global_load_dwordx4 %0, %8, off sc0 sc1\n\t"
                    "global_load_dwordx4 %1, %8, off offset:16 sc0 sc1\n\t"
                    "global_load_dwordx4 %2, %8, off offset:128 sc0 sc1\n\t"
                    "global_load_dwordx4 %3, %8, off offset:144 sc0 sc1\n\t"
                    "global_load_dwordx4 %4, %8, off offset:256 sc0 sc1\n\t"
                    "global_load_dwordx4 %5, %8, off offset:272 sc0 sc1\n\t"
                    "global_load_dwordx4 %6, %8, off offset:384 sc0 sc1\n\t"
                    "global_load_dwordx4 %7, %8, off offset:400 sc0 sc1\n\t"
                    "s_waitcnt vmcnt(0)"
                    : "=&v"(h0), "=&v"(h1), "=&v"(h2), "=&v"(h3),
                      "=&v"(h4), "=&v"(h5), "=&v"(h6), "=&v"(h7)
                    : "v"(hp));
                #define HSTEP(si, va, vb) { \
                    const int ks = kw0 + (si) * 32; \
                    short8 ahi, alo; cvt8((va), (vb), ahi, alo); \
                    const size_t o0 = (size_t)colz * KTOT + ks + koff; \
                    const size_t o1 = o0 + (size_t)HID * KTOT; \
                    const size_t o2 = o1 + (size_t)HID * KTOT; \
                    short8 bzh = *(const short8*)(WBh + o0); \
                    short8 bzl = *(const short8*)(WBl + o0); \
                    short8 brh = *(const short8*)(WBh + o1); \
                    short8 brl = *(const short8*)(WBl + o1); \
                    short8 bnh = *(const short8*)(WBh + o2); \
                    short8 bnl = *(const short8*)(WBl + o2); \
                    aZ = MFMA(ahi, bzh, aZ); aZ = MFMA(ahi, bzl, aZ); aZ = MFMA(alo, bzh, aZ); \
                    aR = MFMA(ahi, brh, aR); aR = MFMA(ahi, brl, aR); aR = MFMA(alo, brh, aR); \
                    aN = MFMA(ahi, bnh, aN); aN = MFMA(ahi, bnl, aN); aN = MFMA(alo, bnh, aN); }
                HSTEP(0, h0, h1)
                HSTEP(1, h2, h3)
                HSTEP(2, h4, h5)
                HSTEP(3, h6, h7)
                #undef HSTEP
            }
            #pragma unroll
            for (int r = 0; r < 4; ++r) {
                red[w][0][r][l] = aZ[r];
                red[w][1][r][l] = aR[r];
                red[w][2][r][l] = aN[r];
            }
        } else {
            const int tp = t + 2;
            if (tp < SEQ) {
                const int colz_g = colz + (w - 8) * HID;
                xproj_gate(x, WBh, WBl, m, tp, koff, colz_g, &ring[tp & 3][w - 8][0][0], l);
            }
        }
        __syncthreads();   // red[t] + (ring slot t+2) published

        if (tid < 256) {
            float sz = 0.f, sr = 0.f, snh = 0.f;
            #pragma unroll
            for (int wv = 0; wv < 8; ++wv) {
                sz  += red[wv][0][r2][l2];
                sr  += red[wv][1][r2][l2];
                snh += red[wv][2][r2][l2];
            }
            const int sl = t & 3;
            sz += ring[sl][0][r2][l2];
            sr += ring[sl][1][r2][l2];
            float snx = ring[sl][2][r2][l2];

            float z   = 1.f / (1.f + __expf(-(sz + bz)));
            float rr  = 1.f / (1.f + __expf(-(sr + br)));
            float pre = snx + bnb + rr * snh;
            float e2  = __expf(2.f * pre);
            float n   = 1.f - 2.f / (e2 + 1.f);
            float h   = (1.f - z) * n + z * hreg;
            hreg = h;
            float* hw = hall + ((size_t)be * SEQ + t) * HID + ce;
            asm volatile("global_store_dword %0, %1, off sc0 sc1"
                         :: "v"(hw), "v"(h) : "memory");
            if (t == SEQ - 1) out[(size_t)be * HID + ce] = h;
            // drain own stores, then this wave arrives (4 arrivals/block)
            asm volatile("s_waitcnt vmcnt(0)" ::: "memory");
            if ((tid & 63) == 0)
                __hip_atomic_fetch_add(dbar, 1u, __ATOMIC_RELEASE,
                                       __HIP_MEMORY_SCOPE_AGENT);
        }

        // every wave polls its domain independently (no extra __syncthreads)
        const unsigned tgt = (unsigned)(t + 1) * 256u;
        while (__hip_atomic_load(dbar, __ATOMIC_RELAXED,
                                 __HIP_MEMORY_SCOPE_AGENT) < tgt)
            __builtin_amdgcn_s_sleep(2);
    }
}

extern "C" void kernel_launch(void* const* d_in, const int* in_sizes, int n_in,
                              void* d_out, int out_size, void* d_ws, size_t ws_size,
                              hipStream_t stream) {
    const float* x   = (const float*)d_in[0];
    const float* Win = (const float*)d_in[1];
    const float* bin = (const float*)d_in[2];
    const float* Wh  = (const float*)d_in[3];
    float* out = (float*)d_out;

    __bf16* WBh = (__bf16*)d_ws;                       // 9.44 MB
    __bf16* WBl = (__bf16*)d_ws + (size_t)WB_ELEMS;    // 9.44 MB
    unsigned* bar = (unsigned*)((char*)d_ws + (size_t)2 * WB_ELEMS * sizeof(__bf16));

    hipMemsetAsync(bar, 0, 1024, stream);   // deterministic across replays
    hipLaunchKernelGGL(build_wt, dim3((WB_ELEMS + 255) / 256), dim3(256), 0, stream,
                       Win, Wh, WBh, WBl);
    hipLaunchKernelGGL(gru_persist, dim3(NBLK), dim3(BLOCK_T), 0, stream,
                       x, bin, WBh, WBl, out, bar);
}

// Round 6
// 11752.879 us; speedup vs baseline: 2.3891x; 2.3891x over previous
//
#include <hip/hip_runtime.h>
#include <math.h>

#define D_IN   512
#define HID    1024
#define SEQ    512
#define NBATCH 64
#define K3     3072
#define KTOT   1536
#define WB_ELEMS (K3 * KTOT)
#define NBLK   256
#define BLOCK_T 704   // 11 waves: 0-7 h-GEMM (K=128 each), 8-10 x-producer (1 gate each)

typedef __attribute__((ext_vector_type(8))) short short8;
typedef __attribute__((ext_vector_type(4))) float f32x4;

#define MFMA(a, b, c) __builtin_amdgcn_mfma_f32_16x16x32_bf16((a), (b), (c), 0, 0, 0)

// ---------------- build fused transposed weight planes (hi/lo bf16) ----------------
__global__ __launch_bounds__(256) void build_wt(const float* __restrict__ Win,
                                                const float* __restrict__ Wh,
                                                __bf16* __restrict__ WBh,
                                                __bf16* __restrict__ WBl) {
    int idx = blockIdx.x * 256 + threadIdx.x;
    if (idx >= WB_ELEMS) return;
    int k   = idx % KTOT;
    int col = idx / KTOT;
    float v = (k < D_IN) ? Win[(size_t)k * K3 + col]
                         : Wh[(size_t)(k - D_IN) * K3 + col];
    __bf16 hi = (__bf16)v;
    WBh[idx] = hi;
    WBl[idx] = (__bf16)(v - (float)hi);
}

__device__ __forceinline__ void cvt8(const f32x4& v0, const f32x4& v1,
                                     short8& ahi, short8& alo) {
    float af[8] = {v0[0], v0[1], v0[2], v0[3], v1[0], v1[1], v1[2], v1[3]};
    #pragma unroll
    for (int j = 0; j < 8; ++j) {
        __bf16 hb = (__bf16)af[j];
        __bf16 lb = (__bf16)(af[j] - (float)hb);
        ahi[j] = __builtin_bit_cast(short, hb);
        alo[j] = __builtin_bit_cast(short, lb);
    }
}

// x-producer: one gate, full K=512, result -> ring slot (16x16 tile, 4 regs/lane)
__device__ __forceinline__ void xproj_gate(const float* __restrict__ x,
                                           const __bf16* __restrict__ WBh,
                                           const __bf16* __restrict__ WBl,
                                           int m, int tp, int koff, int colz_g,
                                           float* __restrict__ ringslot, int l) {
    f32x4 acc = {0.f, 0.f, 0.f, 0.f};
    #pragma unroll
    for (int s = 0; s < 16; ++s) {
        const int ks = s * 32;
        const float* ap = x + ((size_t)m * SEQ + tp) * D_IN + ks + koff;
        f32x4 v0 = *(const f32x4*)ap;
        f32x4 v1 = *(const f32x4*)(ap + 4);
        short8 ahi, alo;
        cvt8(v0, v1, ahi, alo);
        const size_t o = (size_t)colz_g * KTOT + ks + koff;
        short8 bh = *(const short8*)(WBh + o);
        short8 bl = *(const short8*)(WBl + o);
        acc = MFMA(ahi, bh, acc);
        acc = MFMA(ahi, bl, acc);
        acc = MFMA(alo, bh, acc);
    }
    #pragma unroll
    for (int r = 0; r < 4; ++r) ringslot[r * 64 + l] = acc[r];
}

// ---------------- persistent GRU ----------------
// Grid 256 x 704. Block (mq=j&3, nb=xcd+8*(j>>2)), xcd=bid&7.
// h-waves 0-7: K-slice [512+128w, +128); x-waves 8-10: gate w-8, K=512, 2 steps ahead.
// Inter-step sync, per mq-domain (64 blocks), hierarchical:
//   4 epilogue waves -> LDS counter (block-local, ~20cy)
//   4th wave -> 1 global RMW on sub[mq][nb>>3]   (8 RMWs/line)
//   last of sub -> 1 RMW on root[mq]             (8 RMWs/line)
//   all waves poll root (relaxed agent loads). Monotonic counts, replay-safe.
__global__ __launch_bounds__(BLOCK_T, 3) void gru_persist(
        const float* __restrict__ x, const float* __restrict__ bin,
        const __bf16* __restrict__ WBh, const __bf16* __restrict__ WBl,
        float* __restrict__ out, unsigned* __restrict__ bar) {
    __shared__ float red[8][3][4][64];    // h-wave partials: 24KB
    __shared__ float ring[4][3][4][64];   // x_proj ring (4 slots x 3 gates): 12KB
    __shared__ unsigned ecnt;             // block-local epilogue arrivals
    float* hall = out + NBATCH * HID;

    const int tid = threadIdx.x;
    const int l   = tid & 63;
    const int w   = tid >> 6;              // 0..10
    const int xcd = blockIdx.x & 7;
    const int j   = blockIdx.x >> 3;
    const int nb  = xcd + 8 * (j >> 2);
    const int mq  = j & 3;
    const int cb  = nb * 16;

    const int m    = mq * 16 + (l & 15);
    const int koff = (l >> 4) * 8;
    const int colz = cb + (l & 15);
    const bool isH = (w < 8);
    const int kw0  = D_IN + w * 128;       // h-wave K start (global k)

    unsigned* root = bar + mq * 1024;                      // 4KB/domain stride
    unsigned* sub  = bar + mq * 1024 + 32 + (nb >> 3) * 32;

    // epilogue constants
    const int r2 = tid >> 6;
    const int l2 = tid & 63;
    const int be = mq * 16 + (l2 >> 4) * 4 + r2;   // C layout (m89)
    const int ce = cb + (l2 & 15);
    float bz = 0.f, br = 0.f, bnb = 0.f, hreg = 0.f;
    if (tid < 256) {
        bz  = bin[ce];
        br  = bin[HID + ce];
        bnb = bin[2 * HID + ce];
    }
    if (tid == 0) ecnt = 0u;

    // ---- pre-loop: x-waves fill ring slots 0,1
    if (!isH) {
        const int colz_g = colz + (w - 8) * HID;
        xproj_gate(x, WBh, WBl, m, 0, koff, colz_g, &ring[0][w - 8][0][0], l);
        xproj_gate(x, WBh, WBl, m, 1, koff, colz_g, &ring[1][w - 8][0][0], l);
    }
    __syncthreads();

    for (int t = 0; t < SEQ; ++t) {
        if (isH) {
            f32x4 aZ = {0.f,0.f,0.f,0.f}, aR = {0.f,0.f,0.f,0.f}, aN = {0.f,0.f,0.f,0.f};
            if (t > 0) {
                const float* hp = hall + ((size_t)m * SEQ + (t - 1)) * HID + (kw0 - D_IN) + koff;
                f32x4 h0, h1, h2, h3, h4, h5, h6, h7;
                // issue all 8, wait once
                asm volatile(
                    "global_load_dwordx4 %0, %8, off sc0 sc1\n\t"
                    "global_load_dwordx4 %1, %8, off offset:16 sc0 sc1\n\t"
                    "global_load_dwordx4 %2, %8, off offset:128 sc0 sc1\n\t"
                    "global_load_dwordx4 %3, %8, off offset:144 sc0 sc1\n\t"
                    "global_load_dwordx4 %4, %8, off offset:256 sc0 sc1\n\t"
                    "global_load_dwordx4 %5, %8, off offset:272 sc0 sc1\n\t"
                    "global_load_dwordx4 %6, %8, off offset:384 sc0 sc1\n\t"
                    "global_load_dwordx4 %7, %8, off offset:400 sc0 sc1\n\t"
                    "s_waitcnt vmcnt(0)"
                    : "=&v"(h0), "=&v"(h1), "=&v"(h2), "=&v"(h3),
                      "=&v"(h4), "=&v"(h5), "=&v"(h6), "=&v"(h7)
                    : "v"(hp));
                #define HSTEP(si, va, vb) { \
                    const int ks = kw0 + (si) * 32; \
                    short8 ahi, alo; cvt8((va), (vb), ahi, alo); \
                    const size_t o0 = (size_t)colz * KTOT + ks + koff; \
                    const size_t o1 = o0 + (size_t)HID * KTOT; \
                    const size_t o2 = o1 + (size_t)HID * KTOT; \
                    short8 bzh = *(const short8*)(WBh + o0); \
                    short8 bzl = *(const short8*)(WBl + o0); \
                    short8 brh = *(const short8*)(WBh + o1); \
                    short8 brl = *(const short8*)(WBl + o1); \
                    short8 bnh = *(const short8*)(WBh + o2); \
                    short8 bnl = *(const short8*)(WBl + o2); \
                    aZ = MFMA(ahi, bzh, aZ); aZ = MFMA(ahi, bzl, aZ); aZ = MFMA(alo, bzh, aZ); \
                    aR = MFMA(ahi, brh, aR); aR = MFMA(ahi, brl, aR); aR = MFMA(alo, brh, aR); \
                    aN = MFMA(ahi, bnh, aN); aN = MFMA(ahi, bnl, aN); aN = MFMA(alo, bnh, aN); }
                HSTEP(0, h0, h1)
                HSTEP(1, h2, h3)
                HSTEP(2, h4, h5)
                HSTEP(3, h6, h7)
                #undef HSTEP
            }
            #pragma unroll
            for (int r = 0; r < 4; ++r) {
                red[w][0][r][l] = aZ[r];
                red[w][1][r][l] = aR[r];
                red[w][2][r][l] = aN[r];
            }
        } else {
            const int tp = t + 2;
            if (tp < SEQ) {
                const int colz_g = colz + (w - 8) * HID;
                xproj_gate(x, WBh, WBl, m, tp, koff, colz_g, &ring[tp & 3][w - 8][0][0], l);
            }
        }
        __syncthreads();   // red[t] + (ring slot t+2) published

        if (tid < 256) {
            float sz = 0.f, sr = 0.f, snh = 0.f;
            #pragma unroll
            for (int wv = 0; wv < 8; ++wv) {
                sz  += red[wv][0][r2][l2];
                sr  += red[wv][1][r2][l2];
                snh += red[wv][2][r2][l2];
            }
            const int sl = t & 3;
            sz += ring[sl][0][r2][l2];
            sr += ring[sl][1][r2][l2];
            float snx = ring[sl][2][r2][l2];

            float z   = 1.f / (1.f + __expf(-(sz + bz)));
            float rr  = 1.f / (1.f + __expf(-(sr + br)));
            float pre = snx + bnb + rr * snh;
            float e2  = __expf(2.f * pre);
            float n   = 1.f - 2.f / (e2 + 1.f);
            float h   = (1.f - z) * n + z * hreg;
            hreg = h;
            float* hw = hall + ((size_t)be * SEQ + t) * HID + ce;
            asm volatile("global_store_dword %0, %1, off sc0 sc1"
                         :: "v"(hw), "v"(h) : "memory");
            if (t == SEQ - 1) out[(size_t)be * HID + ce] = h;
            // drain own stores, then hierarchical arrival
            asm volatile("s_waitcnt vmcnt(0)" ::: "memory");
            if ((tid & 63) == 0) {
                unsigned eo = __hip_atomic_fetch_add(&ecnt, 1u, __ATOMIC_ACQ_REL,
                                                     __HIP_MEMORY_SCOPE_WORKGROUP);
                if (eo == 4u * (unsigned)(t + 1) - 1u) {
                    // last epilogue wave of this block: one global RMW
                    unsigned so = __hip_atomic_fetch_add(sub, 1u, __ATOMIC_RELEASE,
                                                         __HIP_MEMORY_SCOPE_AGENT);
                    if (so == 8u * (unsigned)(t + 1) - 1u)
                        __hip_atomic_fetch_add(root, 1u, __ATOMIC_RELEASE,
                                               __HIP_MEMORY_SCOPE_AGENT);
                }
            }
        }

        // every wave polls its domain root (plain loads; no RMW contention)
        const unsigned tgt = (unsigned)(t + 1) * 8u;
        while (__hip_atomic_load(root, __ATOMIC_RELAXED,
                                 __HIP_MEMORY_SCOPE_AGENT) < tgt)
            __builtin_amdgcn_s_sleep(2);
    }
}

extern "C" void kernel_launch(void* const* d_in, const int* in_sizes, int n_in,
                              void* d_out, int out_size, void* d_ws, size_t ws_size,
                              hipStream_t stream) {
    const float* x   = (const float*)d_in[0];
    const float* Win = (const float*)d_in[1];
    const float* bin = (const float*)d_in[2];
    const float* Wh  = (const float*)d_in[3];
    float* out = (float*)d_out;

    __bf16* WBh = (__bf16*)d_ws;                       // 9.44 MB
    __bf16* WBl = (__bf16*)d_ws + (size_t)WB_ELEMS;    // 9.44 MB
    unsigned* bar = (unsigned*)((char*)d_ws + (size_t)2 * WB_ELEMS * sizeof(__bf16));

    hipMemsetAsync(bar, 0, 4 * 1024 * sizeof(unsigned), stream);  // replay-safe
    hipLaunchKernelGGL(build_wt, dim3((WB_ELEMS + 255) / 256), dim3(256), 0, stream,
                       Win, Wh, WBh, WBl);
    hipLaunchKernelGGL(gru_persist, dim3(NBLK), dim3(BLOCK_T), 0, stream,
                       x, bin, WBh, WBl, out, bar);
}

// Round 7
// 5292.474 us; speedup vs baseline: 5.3054x; 2.2207x over previous
//
#include <hip/hip_runtime.h>
#include <math.h>

#define D_IN   512
#define HID    1024
#define SEQ    512
#define NBATCH 64
#define K3     3072
#define KTOT   1536
#define WB_ELEMS (K3 * KTOT)
#define NBLK   256
#define BLOCK_T 768   // 12 waves: 0-7 h-part (K=128 each), 8-11 x-part (K=128 each)

typedef __attribute__((ext_vector_type(8))) short short8;
typedef __attribute__((ext_vector_type(4))) float f32x4;

#define MFMA(a, b, c) __builtin_amdgcn_mfma_f32_16x16x32_bf16((a), (b), (c), 0, 0, 0)

// ---------------- build fused transposed weight planes (hi/lo bf16) ----------------
__global__ __launch_bounds__(256) void build_wt(const float* __restrict__ Win,
                                                const float* __restrict__ Wh,
                                                __bf16* __restrict__ WBh,
                                                __bf16* __restrict__ WBl) {
    int idx = blockIdx.x * 256 + threadIdx.x;
    if (idx >= WB_ELEMS) return;
    int k   = idx % KTOT;
    int col = idx / KTOT;
    float v = (k < D_IN) ? Win[(size_t)k * K3 + col]
                         : Wh[(size_t)(k - D_IN) * K3 + col];
    __bf16 hi = (__bf16)v;
    WBh[idx] = hi;
    WBl[idx] = (__bf16)(v - (float)hi);
}

__device__ __forceinline__ void cvt8(const f32x4& v0, const f32x4& v1,
                                     short8& ahi, short8& alo) {
    float af[8] = {v0[0], v0[1], v0[2], v0[3], v1[0], v1[1], v1[2], v1[3]};
    #pragma unroll
    for (int j = 0; j < 8; ++j) {
        __bf16 hb = (__bf16)af[j];
        __bf16 lb = (__bf16)(af[j] - (float)hb);
        ahi[j] = __builtin_bit_cast(short, hb);
        alo[j] = __builtin_bit_cast(short, lb);
    }
}

// ---------------- persistent GRU, weights register-resident ----------------
// Grid 256 x 768 (12 waves, 3/SIMD, 1 block/CU -> co-resident, 32 blocks/XCD).
// Block (mq=j&3, nb=xcd+8*(j>>2)), xcd=bid&7 [sharer co-location on XCD].
// Every wave holds its full weight slice in VGPRs (Bh/Bl[3][4] = 96 VGPR),
// loaded ONCE. Waves 0-7: h-part k in [512+128w, +128), sc1-coherent A loads.
// Waves 8-11: x-part k in [128(w-8), +128), normal cached A loads.
// Inter-step sync per mq-domain (64 blocks, fully independent):
//   4 epilogue waves -> LDS ecnt; 4th -> sub RMW (8/line); last -> root RMW
//   (8/line); ONLY tid0 polls root (64 pollers/line); __syncthreads releases.
__global__ __launch_bounds__(BLOCK_T, 3) void gru_persist(
        const float* __restrict__ x, const float* __restrict__ bin,
        const __bf16* __restrict__ WBh, const __bf16* __restrict__ WBl,
        float* __restrict__ out, unsigned* __restrict__ bar) {
    __shared__ float red[12][3][4][64];   // 36 KB
    __shared__ unsigned ecnt;
    float* hall = out + NBATCH * HID;

    const int tid = threadIdx.x;
    const int l   = tid & 63;
    const int w   = tid >> 6;              // 0..11
    const int xcd = blockIdx.x & 7;
    const int j   = blockIdx.x >> 3;
    const int nb  = xcd + 8 * (j >> 2);
    const int mq  = j & 3;
    const int cb  = nb * 16;

    const int m    = mq * 16 + (l & 15);
    const int koff = (l >> 4) * 8;
    const int colz = cb + (l & 15);
    const bool isH = (w < 8);
    const int kbase = isH ? (D_IN + 128 * w) : (128 * (w - 8));

    unsigned* root = bar + mq * 1024;                       // 4KB/domain stride
    unsigned* sub  = bar + mq * 1024 + 64 + (nb >> 3) * 64; // 256B-separated

    // ---- one-time: weight slice into registers (static-indexed, stays in VGPR)
    short8 Bh[3][4], Bl[3][4];
    #pragma unroll
    for (int g = 0; g < 3; ++g) {
        #pragma unroll
        for (int s = 0; s < 4; ++s) {
            const size_t o = (size_t)(colz + g * HID) * KTOT + kbase + 32 * s + koff;
            Bh[g][s] = *(const short8*)(WBh + o);
            Bl[g][s] = *(const short8*)(WBl + o);
        }
    }

    // epilogue constants (waves 0-3)
    const int r2 = tid >> 6;
    const int l2 = tid & 63;
    const int be = mq * 16 + (l2 >> 4) * 4 + r2;   // C layout (m89)
    const int ce = cb + (l2 & 15);
    float bz = 0.f, br = 0.f, bnb = 0.f, hreg = 0.f;
    if (tid < 256) {
        bz  = bin[ce];
        br  = bin[HID + ce];
        bnb = bin[2 * HID + ce];
    }
    if (tid == 0) ecnt = 0u;
    // (ecnt visible before first epilogue via the t=0 red-publish barrier)

    for (int t = 0; t < SEQ; ++t) {
        f32x4 aZ = {0.f,0.f,0.f,0.f}, aR = {0.f,0.f,0.f,0.f}, aN = {0.f,0.f,0.f,0.f};

        if (isH) {
            if (t > 0) {
                const float* hp = hall + ((size_t)m * SEQ + (t - 1)) * HID
                                  + (kbase - D_IN) + koff;
                f32x4 h0, h1, h2, h3, h4, h5, h6, h7;
                asm volatile(
                    "global_load_dwordx4 %0, %8, off sc0 sc1\n\t"
                    "global_load_dwordx4 %1, %8, off offset:16 sc0 sc1\n\t"
                    "global_load_dwordx4 %2, %8, off offset:128 sc0 sc1\n\t"
                    "global_load_dwordx4 %3, %8, off offset:144 sc0 sc1\n\t"
                    "global_load_dwordx4 %4, %8, off offset:256 sc0 sc1\n\t"
                    "global_load_dwordx4 %5, %8, off offset:272 sc0 sc1\n\t"
                    "global_load_dwordx4 %6, %8, off offset:384 sc0 sc1\n\t"
                    "global_load_dwordx4 %7, %8, off offset:400 sc0 sc1\n\t"
                    "s_waitcnt vmcnt(0)"
                    : "=&v"(h0), "=&v"(h1), "=&v"(h2), "=&v"(h3),
                      "=&v"(h4), "=&v"(h5), "=&v"(h6), "=&v"(h7)
                    : "v"(hp));
                #define SUBT(si, va, vb) { \
                    short8 ahi, alo; cvt8((va), (vb), ahi, alo); \
                    aZ = MFMA(ahi, Bh[0][si], aZ); aZ = MFMA(ahi, Bl[0][si], aZ); \
                    aZ = MFMA(alo, Bh[0][si], aZ); \
                    aR = MFMA(ahi, Bh[1][si], aR); aR = MFMA(ahi, Bl[1][si], aR); \
                    aR = MFMA(alo, Bh[1][si], aR); \
                    aN = MFMA(ahi, Bh[2][si], aN); aN = MFMA(ahi, Bl[2][si], aN); \
                    aN = MFMA(alo, Bh[2][si], aN); }
                SUBT(0, h0, h1)
                SUBT(1, h2, h3)
                SUBT(2, h4, h5)
                SUBT(3, h6, h7)
                #undef SUBT
            }
        } else {
            const float* xp = x + ((size_t)m * SEQ + t) * D_IN + kbase + koff;
            #pragma unroll
            for (int s = 0; s < 4; ++s) {
                f32x4 v0 = *(const f32x4*)(xp + 32 * s);
                f32x4 v1 = *(const f32x4*)(xp + 32 * s + 4);
                short8 ahi, alo;
                cvt8(v0, v1, ahi, alo);
                aZ = MFMA(ahi, Bh[0][s], aZ); aZ = MFMA(ahi, Bl[0][s], aZ);
                aZ = MFMA(alo, Bh[0][s], aZ);
                aR = MFMA(ahi, Bh[1][s], aR); aR = MFMA(ahi, Bl[1][s], aR);
                aR = MFMA(alo, Bh[1][s], aR);
                aN = MFMA(ahi, Bh[2][s], aN); aN = MFMA(ahi, Bl[2][s], aN);
                aN = MFMA(alo, Bh[2][s], aN);
            }
        }

        #pragma unroll
        for (int r = 0; r < 4; ++r) {
            red[w][0][r][l] = aZ[r];
            red[w][1][r][l] = aR[r];
            red[w][2][r][l] = aN[r];
        }
        __syncthreads();

        if (tid < 256) {
            float sz = 0.f, sr = 0.f, snx = 0.f, snh = 0.f;
            #pragma unroll
            for (int wv = 0; wv < 8; ++wv) {
                sz  += red[wv][0][r2][l2];
                sr  += red[wv][1][r2][l2];
                snh += red[wv][2][r2][l2];
            }
            #pragma unroll
            for (int wv = 8; wv < 12; ++wv) {
                sz  += red[wv][0][r2][l2];
                sr  += red[wv][1][r2][l2];
                snx += red[wv][2][r2][l2];
            }
            float z   = 1.f / (1.f + __expf(-(sz + bz)));
            float rr  = 1.f / (1.f + __expf(-(sr + br)));
            float pre = snx + bnb + rr * snh;
            float e2  = __expf(2.f * pre);
            float n   = 1.f - 2.f / (e2 + 1.f);
            float h   = (1.f - z) * n + z * hreg;
            hreg = h;
            float* hw = hall + ((size_t)be * SEQ + t) * HID + ce;
            asm volatile("global_store_dword %0, %1, off sc0 sc1"
                         :: "v"(hw), "v"(h) : "memory");
            if (t == SEQ - 1) out[(size_t)be * HID + ce] = h;
            asm volatile("s_waitcnt vmcnt(0)" ::: "memory");
            if ((tid & 63) == 0) {
                unsigned eo = __hip_atomic_fetch_add(&ecnt, 1u, __ATOMIC_ACQ_REL,
                                                     __HIP_MEMORY_SCOPE_WORKGROUP);
                if (eo == 4u * (unsigned)(t + 1) - 1u) {
                    unsigned so = __hip_atomic_fetch_add(sub, 1u, __ATOMIC_RELEASE,
                                                         __HIP_MEMORY_SCOPE_AGENT);
                    if (so == 8u * (unsigned)(t + 1) - 1u)
                        __hip_atomic_fetch_add(root, 1u, __ATOMIC_RELEASE,
                                               __HIP_MEMORY_SCOPE_AGENT);
                }
            }
        }

        // single poller per block; release via barrier
        if (tid == 0) {
            const unsigned tgt = (unsigned)(t + 1) * 8u;
            while (__hip_atomic_load(root, __ATOMIC_RELAXED,
                                     __HIP_MEMORY_SCOPE_AGENT) < tgt)
                __builtin_amdgcn_s_sleep(4);
        }
        __syncthreads();
    }
}

extern "C" void kernel_launch(void* const* d_in, const int* in_sizes, int n_in,
                              void* d_out, int out_size, void* d_ws, size_t ws_size,
                              hipStream_t stream) {
    const float* x   = (const float*)d_in[0];
    const float* Win = (const float*)d_in[1];
    const float* bin = (const float*)d_in[2];
    const float* Wh  = (const float*)d_in[3];
    float* out = (float*)d_out;

    __bf16* WBh = (__bf16*)d_ws;                       // 9.44 MB
    __bf16* WBl = (__bf16*)d_ws + (size_t)WB_ELEMS;    // 9.44 MB
    unsigned* bar = (unsigned*)((char*)d_ws + (size_t)2 * WB_ELEMS * sizeof(__bf16));

    hipMemsetAsync(bar, 0, 4 * 1024 * sizeof(unsigned), stream);  // replay-safe
    hipLaunchKernelGGL(build_wt, dim3((WB_ELEMS + 255) / 256), dim3(256), 0, stream,
                       Win, Wh, WBh, WBl);
    hipLaunchKernelGGL(gru_persist, dim3(NBLK), dim3(BLOCK_T), 0, stream,
                       x, bin, WBh, WBl, out, bar);
}

// Round 8
// 4568.166 us; speedup vs baseline: 6.1466x; 1.1586x over previous
//
#include <hip/hip_runtime.h>
#include <math.h>

#define D_IN   512
#define HID    1024
#define SEQ    512
#define NBATCH 64
#define K3     3072
#define KTOT   1536
#define WB_ELEMS (K3 * KTOT)
#define NBLK   256
#define BLOCK_T 768   // 12 waves: 0-7 h-part (K=128 each), 8-11 x-part (K=128 each)

typedef __attribute__((ext_vector_type(8))) short short8;
typedef __attribute__((ext_vector_type(4))) float f32x4;

#define MFMA(a, b, c) __builtin_amdgcn_mfma_f32_16x16x32_bf16((a), (b), (c), 0, 0, 0)

// ---------------- build fused transposed weight planes (hi/lo bf16) ----------------
__global__ __launch_bounds__(256) void build_wt(const float* __restrict__ Win,
                                                const float* __restrict__ Wh,
                                                __bf16* __restrict__ WBh,
                                                __bf16* __restrict__ WBl) {
    int idx = blockIdx.x * 256 + threadIdx.x;
    if (idx >= WB_ELEMS) return;
    int k   = idx % KTOT;
    int col = idx / KTOT;
    float v = (k < D_IN) ? Win[(size_t)k * K3 + col]
                         : Wh[(size_t)(k - D_IN) * K3 + col];
    __bf16 hi = (__bf16)v;
    WBh[idx] = hi;
    WBl[idx] = (__bf16)(v - (float)hi);
}

__device__ __forceinline__ void cvt8(const f32x4& v0, const f32x4& v1,
                                     short8& ahi, short8& alo) {
    float af[8] = {v0[0], v0[1], v0[2], v0[3], v1[0], v1[1], v1[2], v1[3]};
    #pragma unroll
    for (int j = 0; j < 8; ++j) {
        __bf16 hb = (__bf16)af[j];
        __bf16 lb = (__bf16)(af[j] - (float)hb);
        ahi[j] = __builtin_bit_cast(short, hb);
        alo[j] = __builtin_bit_cast(short, lb);
    }
}

// ---------------- persistent GRU: reg-resident weights + dataflow sync ----------------
// Grid 256 x 768 (12 waves). Block (mq=j&3, nb=xcd+8*(j>>2)), xcd=bid&7.
// Weights laundered into VGPRs via asm (compiler cannot rematerialize).
// Sync: NO global barrier. gc[mq][g] (g = col-group of 128) bumped once per
// step by each of its 8 producer blocks after store-drain; consumer h-wave w
// polls gc[mq][w] >= 8*t before loading h[t-1] cols [128w,128w+128).
__global__ __launch_bounds__(BLOCK_T, 3) void gru_persist(
        const float* __restrict__ x, const float* __restrict__ bin,
        const __bf16* __restrict__ WBh, const __bf16* __restrict__ WBl,
        float* __restrict__ out, unsigned* __restrict__ bar) {
    __shared__ float red[12][3][4][64];   // 36 KB
    __shared__ unsigned ecnt;
    float* hall = out + NBATCH * HID;

    const int tid = threadIdx.x;
    const int l   = tid & 63;
    const int w   = tid >> 6;              // 0..11
    const int xcd = blockIdx.x & 7;
    const int j   = blockIdx.x >> 3;
    const int nb  = xcd + 8 * (j >> 2);
    const int mq  = j & 3;
    const int cb  = nb * 16;

    const int m    = mq * 16 + (l & 15);
    const int koff = (l >> 4) * 8;
    const int colz = cb + (l & 15);
    const bool isH = (w < 8);
    const int kbase = isH ? (D_IN + 128 * w) : (128 * (w - 8));

    unsigned* gcons = bar + mq * 1024 + w * 64;          // consumer poll target (h-waves)
    unsigned* gprod = bar + mq * 1024 + (nb >> 3) * 64;  // producer bump (own col-group)

    // ---- one-time: weight slice into registers, then LAUNDER so the
    // per-step "memory" clobbers can't force rematerialization from L2.
    short8 Bh[3][4], Bl[3][4];
    #pragma unroll
    for (int g = 0; g < 3; ++g) {
        #pragma unroll
        for (int s = 0; s < 4; ++s) {
            const size_t o = (size_t)(colz + g * HID) * KTOT + kbase + 32 * s + koff;
            Bh[g][s] = *(const short8*)(WBh + o);
            Bl[g][s] = *(const short8*)(WBl + o);
        }
    }
    #pragma unroll
    for (int g = 0; g < 3; ++g) {
        #pragma unroll
        for (int s = 0; s < 4; ++s) {
            asm volatile("" : "+v"(Bh[g][s]));
            asm volatile("" : "+v"(Bl[g][s]));
        }
    }

    // epilogue constants (waves 0-3)
    const int r2 = tid >> 6;
    const int l2 = tid & 63;
    const int be = mq * 16 + (l2 >> 4) * 4 + r2;   // C layout (m89)
    const int ce = cb + (l2 & 15);
    float bz = 0.f, br = 0.f, bnb = 0.f, hreg = 0.f;
    if (tid < 256) {
        bz  = bin[ce];
        br  = bin[HID + ce];
        bnb = bin[2 * HID + ce];
    }
    asm volatile("" : "+v"(bz), "+v"(br), "+v"(bnb));
    if (tid == 0) ecnt = 0u;

    for (int t = 0; t < SEQ; ++t) {
        f32x4 aZ = {0.f,0.f,0.f,0.f}, aR = {0.f,0.f,0.f,0.f}, aN = {0.f,0.f,0.f,0.f};

        if (isH) {
            if (t > 0) {
                // dataflow wait: my 128-col h slice fully stored for step t-1
                const unsigned tgt = 8u * (unsigned)t;
                while (__hip_atomic_load(gcons, __ATOMIC_RELAXED,
                                         __HIP_MEMORY_SCOPE_AGENT) < tgt)
                    __builtin_amdgcn_s_sleep(2);

                const float* hp = hall + ((size_t)m * SEQ + (t - 1)) * HID
                                  + (kbase - D_IN) + koff;
                f32x4 h0, h1, h2, h3, h4, h5, h6, h7;
                asm volatile(
                    "global_load_dwordx4 %0, %8, off sc0 sc1\n\t"
                    "global_load_dwordx4 %1, %8, off offset:16 sc0 sc1\n\t"
                    "global_load_dwordx4 %2, %8, off offset:128 sc0 sc1\n\t"
                    "global_load_dwordx4 %3, %8, off offset:144 sc0 sc1\n\t"
                    "global_load_dwordx4 %4, %8, off offset:256 sc0 sc1\n\t"
                    "global_load_dwordx4 %5, %8, off offset:272 sc0 sc1\n\t"
                    "global_load_dwordx4 %6, %8, off offset:384 sc0 sc1\n\t"
                    "global_load_dwordx4 %7, %8, off offset:400 sc0 sc1\n\t"
                    "s_waitcnt vmcnt(0)"
                    : "=&v"(h0), "=&v"(h1), "=&v"(h2), "=&v"(h3),
                      "=&v"(h4), "=&v"(h5), "=&v"(h6), "=&v"(h7)
                    : "v"(hp));
                #define SUBT(si, va, vb) { \
                    short8 ahi, alo; cvt8((va), (vb), ahi, alo); \
                    aZ = MFMA(ahi, Bh[0][si], aZ); aZ = MFMA(ahi, Bl[0][si], aZ); \
                    aZ = MFMA(alo, Bh[0][si], aZ); \
                    aR = MFMA(ahi, Bh[1][si], aR); aR = MFMA(ahi, Bl[1][si], aR); \
                    aR = MFMA(alo, Bh[1][si], aR); \
                    aN = MFMA(ahi, Bh[2][si], aN); aN = MFMA(ahi, Bl[2][si], aN); \
                    aN = MFMA(alo, Bh[2][si], aN); }
                SUBT(0, h0, h1)
                SUBT(1, h2, h3)
                SUBT(2, h4, h5)
                SUBT(3, h6, h7)
                #undef SUBT
            }
        } else {
            const float* xp = x + ((size_t)m * SEQ + t) * D_IN + kbase + koff;
            #pragma unroll
            for (int s = 0; s < 4; ++s) {
                f32x4 v0 = *(const f32x4*)(xp + 32 * s);
                f32x4 v1 = *(const f32x4*)(xp + 32 * s + 4);
                short8 ahi, alo;
                cvt8(v0, v1, ahi, alo);
                aZ = MFMA(ahi, Bh[0][s], aZ); aZ = MFMA(ahi, Bl[0][s], aZ);
                aZ = MFMA(alo, Bh[0][s], aZ);
                aR = MFMA(ahi, Bh[1][s], aR); aR = MFMA(ahi, Bl[1][s], aR);
                aR = MFMA(alo, Bh[1][s], aR);
                aN = MFMA(ahi, Bh[2][s], aN); aN = MFMA(ahi, Bl[2][s], aN);
                aN = MFMA(alo, Bh[2][s], aN);
            }
        }

        #pragma unroll
        for (int r = 0; r < 4; ++r) {
            red[w][0][r][l] = aZ[r];
            red[w][1][r][l] = aR[r];
            red[w][2][r][l] = aN[r];
        }
        __syncthreads();   // red[t] published

        if (tid < 256) {
            float sz = 0.f, sr = 0.f, snx = 0.f, snh = 0.f;
            #pragma unroll
            for (int wv = 0; wv < 8; ++wv) {
                sz  += red[wv][0][r2][l2];
                sr  += red[wv][1][r2][l2];
                snh += red[wv][2][r2][l2];
            }
            #pragma unroll
            for (int wv = 8; wv < 12; ++wv) {
                sz  += red[wv][0][r2][l2];
                sr  += red[wv][1][r2][l2];
                snx += red[wv][2][r2][l2];
            }
            float z   = 1.f / (1.f + __expf(-(sz + bz)));
            float rr  = 1.f / (1.f + __expf(-(sr + br)));
            float pre = snx + bnb + rr * snh;
            float e2  = __expf(2.f * pre);
            float n   = 1.f - 2.f / (e2 + 1.f);
            float h   = (1.f - z) * n + z * hreg;
            hreg = h;
            float* hw = hall + ((size_t)be * SEQ + t) * HID + ce;
            asm volatile("global_store_dword %0, %1, off sc0 sc1"
                         :: "v"(hw), "v"(h) : "memory");
            if (t == SEQ - 1) out[(size_t)be * HID + ce] = h;
            // drain own stores; last epilogue wave publishes this block's step
            asm volatile("s_waitcnt vmcnt(0)" ::: "memory");
            if ((tid & 63) == 0) {
                unsigned eo = __hip_atomic_fetch_add(&ecnt, 1u, __ATOMIC_ACQ_REL,
                                                     __HIP_MEMORY_SCOPE_WORKGROUP);
                if (eo == 4u * (unsigned)(t + 1) - 1u)
                    __hip_atomic_fetch_add(gprod, 1u, __ATOMIC_RELEASE,
                                           __HIP_MEMORY_SCOPE_AGENT);
            }
        }
        __syncthreads();   // red WAR: next step's writes wait for epilogue reads
    }
}

extern "C" void kernel_launch(void* const* d_in, const int* in_sizes, int n_in,
                              void* d_out, int out_size, void* d_ws, size_t ws_size,
                              hipStream_t stream) {
    const float* x   = (const float*)d_in[0];
    const float* Win = (const float*)d_in[1];
    const float* bin = (const float*)d_in[2];
    const float* Wh  = (const float*)d_in[3];
    float* out = (float*)d_out;

    __bf16* WBh = (__bf16*)d_ws;                       // 9.44 MB
    __bf16* WBl = (__bf16*)d_ws + (size_t)WB_ELEMS;    // 9.44 MB
    unsigned* bar = (unsigned*)((char*)d_ws + (size_t)2 * WB_ELEMS * sizeof(__bf16));

    hipMemsetAsync(bar, 0, 16384, stream);  // gc counters: replay-safe reset
    hipLaunchKernelGGL(build_wt, dim3((WB_ELEMS + 255) / 256), dim3(256), 0, stream,
                       Win, Wh, WBh, WBl);
    hipLaunchKernelGGL(gru_persist, dim3(NBLK), dim3(BLOCK_T), 0, stream,
                       x, bin, WBh, WBl, out, bar);
}

// Round 9
// 4274.931 us; speedup vs baseline: 6.5682x; 1.0686x over previous
//
#include <hip/hip_runtime.h>
#include <math.h>

#define D_IN   512
#define HID    1024
#define SEQ    512
#define NBATCH 64
#define K3     3072
#define KTOT   1536
#define WB_ELEMS (K3 * KTOT)
#define NBLK   256
#define BLOCK_T 768   // 12 waves: 0-7 h-part (K=128 each), 8-11 x-part (K=128 each)

typedef __attribute__((ext_vector_type(8))) short short8;
typedef __attribute__((ext_vector_type(4))) float f32x4;

#define MFMA(a, b, c) __builtin_amdgcn_mfma_f32_16x16x32_bf16((a), (b), (c), 0, 0, 0)

// ---------------- build fused transposed weight planes (hi/lo bf16) ----------------
__global__ __launch_bounds__(256) void build_wt(const float* __restrict__ Win,
                                                const float* __restrict__ Wh,
                                                __bf16* __restrict__ WBh,
                                                __bf16* __restrict__ WBl) {
    int idx = blockIdx.x * 256 + threadIdx.x;
    if (idx >= WB_ELEMS) return;
    int k   = idx % KTOT;
    int col = idx / KTOT;
    float v = (k < D_IN) ? Win[(size_t)k * K3 + col]
                         : Wh[(size_t)(k - D_IN) * K3 + col];
    __bf16 hi = (__bf16)v;
    WBh[idx] = hi;
    WBl[idx] = (__bf16)(v - (float)hi);
}

__device__ __forceinline__ void cvt8(const f32x4& v0, const f32x4& v1,
                                     short8& ahi, short8& alo) {
    float af[8] = {v0[0], v0[1], v0[2], v0[3], v1[0], v1[1], v1[2], v1[3]};
    #pragma unroll
    for (int j = 0; j < 8; ++j) {
        __bf16 hb = (__bf16)af[j];
        __bf16 lb = (__bf16)(af[j] - (float)hb);
        ahi[j] = __builtin_bit_cast(short, hb);
        alo[j] = __builtin_bit_cast(short, lb);
    }
}

// ---------------- persistent GRU: reg-resident weights + dataflow sync ----------------
// Grid 256 x 768 (12 waves). Block (mq=j&3, nb=xcd+8*(j>>2)), xcd=bid&7.
// amdgpu_waves_per_eu(3,3): pin allocator to the REAL occupancy (1 block/CU,
// 3 waves/SIMD, cap 168 VGPR) so the 96-VGPR weight slice is NOT spilled.
// (launch_bounds(768,3) let the allocator target 6 waves/SIMD = 84 VGPR for a
// second resident block that never exists -> weights spilled to scratch.)
// Sync: NO global barrier. gc[mq][g] (g = col-group of 128) bumped once per
// step by each of its 8 producer blocks after store-drain; consumer h-wave w
// polls gc[mq][w] >= 8*t before loading h[t-1] cols [128w,128w+128).
__global__ __attribute__((amdgpu_waves_per_eu(3, 3)))
__launch_bounds__(BLOCK_T) void gru_persist(
        const float* __restrict__ x, const float* __restrict__ bin,
        const __bf16* __restrict__ WBh, const __bf16* __restrict__ WBl,
        float* __restrict__ out, unsigned* __restrict__ bar) {
    __shared__ float red[12][3][4][64];   // 36 KB
    __shared__ unsigned ecnt;
    float* hall = out + NBATCH * HID;

    const int tid = threadIdx.x;
    const int l   = tid & 63;
    const int w   = tid >> 6;              // 0..11
    const int xcd = blockIdx.x & 7;
    const int j   = blockIdx.x >> 3;
    const int nb  = xcd + 8 * (j >> 2);
    const int mq  = j & 3;
    const int cb  = nb * 16;

    const int m    = mq * 16 + (l & 15);
    const int koff = (l >> 4) * 8;
    const int colz = cb + (l & 15);
    const bool isH = (w < 8);
    const int kbase = isH ? (D_IN + 128 * w) : (128 * (w - 8));

    unsigned* gcons = bar + mq * 1024 + w * 64;          // consumer poll target (h-waves)
    unsigned* gprod = bar + mq * 1024 + (nb >> 3) * 64;  // producer bump (own col-group)

    // ---- one-time: weight slice into registers, then LAUNDER so the
    // per-step "memory" clobbers can't force rematerialization from L2.
    short8 Bh[3][4], Bl[3][4];
    #pragma unroll
    for (int g = 0; g < 3; ++g) {
        #pragma unroll
        for (int s = 0; s < 4; ++s) {
            const size_t o = (size_t)(colz + g * HID) * KTOT + kbase + 32 * s + koff;
            Bh[g][s] = *(const short8*)(WBh + o);
            Bl[g][s] = *(const short8*)(WBl + o);
        }
    }
    #pragma unroll
    for (int g = 0; g < 3; ++g) {
        #pragma unroll
        for (int s = 0; s < 4; ++s) {
            asm volatile("" : "+v"(Bh[g][s]));
            asm volatile("" : "+v"(Bl[g][s]));
        }
    }

    // epilogue constants (waves 0-3)
    const int r2 = tid >> 6;
    const int l2 = tid & 63;
    const int be = mq * 16 + (l2 >> 4) * 4 + r2;   // C layout (m89)
    const int ce = cb + (l2 & 15);
    float bz = 0.f, br = 0.f, bnb = 0.f, hreg = 0.f;
    if (tid < 256) {
        bz  = bin[ce];
        br  = bin[HID + ce];
        bnb = bin[2 * HID + ce];
    }
    asm volatile("" : "+v"(bz), "+v"(br), "+v"(bnb));
    if (tid == 0) ecnt = 0u;

    for (int t = 0; t < SEQ; ++t) {
        f32x4 aZ = {0.f,0.f,0.f,0.f}, aR = {0.f,0.f,0.f,0.f}, aN = {0.f,0.f,0.f,0.f};

        if (isH) {
            if (t > 0) {
                // dataflow wait: my 128-col h slice fully stored for step t-1
                const unsigned tgt = 8u * (unsigned)t;
                while (__hip_atomic_load(gcons, __ATOMIC_RELAXED,
                                         __HIP_MEMORY_SCOPE_AGENT) < tgt)
                    __builtin_amdgcn_s_sleep(2);

                const float* hp = hall + ((size_t)m * SEQ + (t - 1)) * HID
                                  + (kbase - D_IN) + koff;
                f32x4 h0, h1, h2, h3, h4, h5, h6, h7;
                asm volatile(
                    "global_load_dwordx4 %0, %8, off sc0 sc1\n\t"
                    "global_load_dwordx4 %1, %8, off offset:16 sc0 sc1\n\t"
                    "global_load_dwordx4 %2, %8, off offset:128 sc0 sc1\n\t"
                    "global_load_dwordx4 %3, %8, off offset:144 sc0 sc1\n\t"
                    "global_load_dwordx4 %4, %8, off offset:256 sc0 sc1\n\t"
                    "global_load_dwordx4 %5, %8, off offset:272 sc0 sc1\n\t"
                    "global_load_dwordx4 %6, %8, off offset:384 sc0 sc1\n\t"
                    "global_load_dwordx4 %7, %8, off offset:400 sc0 sc1\n\t"
                    "s_waitcnt vmcnt(0)"
                    : "=&v"(h0), "=&v"(h1), "=&v"(h2), "=&v"(h3),
                      "=&v"(h4), "=&v"(h5), "=&v"(h6), "=&v"(h7)
                    : "v"(hp));
                #define SUBT(si, va, vb) { \
                    short8 ahi, alo; cvt8((va), (vb), ahi, alo); \
                    aZ = MFMA(ahi, Bh[0][si], aZ); aZ = MFMA(ahi, Bl[0][si], aZ); \
                    aZ = MFMA(alo, Bh[0][si], aZ); \
                    aR = MFMA(ahi, Bh[1][si], aR); aR = MFMA(ahi, Bl[1][si], aR); \
                    aR = MFMA(alo, Bh[1][si], aR); \
                    aN = MFMA(ahi, Bh[2][si], aN); aN = MFMA(ahi, Bl[2][si], aN); \
                    aN = MFMA(alo, Bh[2][si], aN); }
                SUBT(0, h0, h1)
                SUBT(1, h2, h3)
                SUBT(2, h4, h5)
                SUBT(3, h6, h7)
                #undef SUBT
            }
        } else {
            const float* xp = x + ((size_t)m * SEQ + t) * D_IN + kbase + koff;
            #pragma unroll
            for (int s = 0; s < 4; ++s) {
                f32x4 v0 = *(const f32x4*)(xp + 32 * s);
                f32x4 v1 = *(const f32x4*)(xp + 32 * s + 4);
                short8 ahi, alo;
                cvt8(v0, v1, ahi, alo);
                aZ = MFMA(ahi, Bh[0][s], aZ); aZ = MFMA(ahi, Bl[0][s], aZ);
                aZ = MFMA(alo, Bh[0][s], aZ);
                aR = MFMA(ahi, Bh[1][s], aR); aR = MFMA(ahi, Bl[1][s], aR);
                aR = MFMA(alo, Bh[1][s], aR);
                aN = MFMA(ahi, Bh[2][s], aN); aN = MFMA(ahi, Bl[2][s], aN);
                aN = MFMA(alo, Bh[2][s], aN);
            }
        }

        #pragma unroll
        for (int r = 0; r < 4; ++r) {
            red[w][0][r][l] = aZ[r];
            red[w][1][r][l] = aR[r];
            red[w][2][r][l] = aN[r];
        }
        __syncthreads();   // red[t] published

        if (tid < 256) {
            float sz = 0.f, sr = 0.f, snx = 0.f, snh = 0.f;
            #pragma unroll
            for (int wv = 0; wv < 8; ++wv) {
                sz  += red[wv][0][r2][l2];
                sr  += red[wv][1][r2][l2];
                snh += red[wv][2][r2][l2];
            }
            #pragma unroll
            for (int wv = 8; wv < 12; ++wv) {
                sz  += red[wv][0][r2][l2];
                sr  += red[wv][1][r2][l2];
                snx += red[wv][2][r2][l2];
            }
            float z   = 1.f / (1.f + __expf(-(sz + bz)));
            float rr  = 1.f / (1.f + __expf(-(sr + br)));
            float pre = snx + bnb + rr * snh;
            float e2  = __expf(2.f * pre);
            float n   = 1.f - 2.f / (e2 + 1.f);
            float h   = (1.f - z) * n + z * hreg;
            hreg = h;
            float* hw = hall + ((size_t)be * SEQ + t) * HID + ce;
            asm volatile("global_store_dword %0, %1, off sc0 sc1"
                         :: "v"(hw), "v"(h) : "memory");
            if (t == SEQ - 1) out[(size_t)be * HID + ce] = h;
            // drain own stores; last epilogue wave publishes this block's step
            asm volatile("s_waitcnt vmcnt(0)" ::: "memory");
            if ((tid & 63) == 0) {
                unsigned eo = __hip_atomic_fetch_add(&ecnt, 1u, __ATOMIC_ACQ_REL,
                                                     __HIP_MEMORY_SCOPE_WORKGROUP);
                if (eo == 4u * (unsigned)(t + 1) - 1u)
                    __hip_atomic_fetch_add(gprod, 1u, __ATOMIC_RELEASE,
                                           __HIP_MEMORY_SCOPE_AGENT);
            }
        }
        __syncthreads();   // red WAR: next step's writes wait for epilogue reads
    }
}

extern "C" void kernel_launch(void* const* d_in, const int* in_sizes, int n_in,
                              void* d_out, int out_size, void* d_ws, size_t ws_size,
                              hipStream_t stream) {
    const float* x   = (const float*)d_in[0];
    const float* Win = (const float*)d_in[1];
    const float* bin = (const float*)d_in[2];
    const float* Wh  = (const float*)d_in[3];
    float* out = (float*)d_out;

    __bf16* WBh = (__bf16*)d_ws;                       // 9.44 MB
    __bf16* WBl = (__bf16*)d_ws + (size_t)WB_ELEMS;    // 9.44 MB
    unsigned* bar = (unsigned*)((char*)d_ws + (size_t)2 * WB_ELEMS * sizeof(__bf16));

    hipMemsetAsync(bar, 0, 16384, stream);  // gc counters: replay-safe reset
    hipLaunchKernelGGL(build_wt, dim3((WB_ELEMS + 255) / 256), dim3(256), 0, stream,
                       Win, Wh, WBh, WBl);
    hipLaunchKernelGGL(gru_persist, dim3(NBLK), dim3(BLOCK_T), 0, stream,
                       x, bin, WBh, WBl, out, bar);
}